// Round 6
// baseline (217.431 us; speedup 1.0000x reference)
//
#include <hip/hip_runtime.h>
#include <hip/hip_bf16.h>
#include <math.h>

#define DIM 768
#define NHEADS 12
#define HD 64
#define SEQ 4096
#define KSPLIT 4

typedef __bf16 bf16x8 __attribute__((ext_vector_type(8)));
typedef float f32x4 __attribute__((ext_vector_type(4)));

// Native bf16 convert (RNE) — used outside flash.
__device__ inline ushort f2bf(float f) {
    __bf16 b = (__bf16)f;
    union { __bf16 b; ushort u; } v; v.b = b;
    return v.u;
}

// Manual RNE twiddle — used inside flash (byte-identical to the r10 kernel;
// unbiased RNE is REQUIRED here: v_cvt_pk_bf16_f32 biased P downward and
// failed the absmax check at 4.3e-2 in round 1).
__device__ inline ushort f2bf_tw(float f) {
    union { float f; uint u; } v; v.f = f;
    uint r = v.u + 0x7FFF + ((v.u >> 16) & 1);
    return (ushort)(r >> 16);
}

// global -> LDS direct copy, 16B per lane. LDS dest is WAVE-UNIFORM base
// (hw adds lane*16); global src is per-lane. (m97 staging, +69% on this
// exact 128^2 2-barrier GEMM structure vs reg-staged float4.)
__device__ inline void gload16(const ushort* gsrc, ushort* lbase) {
    __builtin_amdgcn_global_load_lds(
        (const __attribute__((address_space(1))) uint*)gsrc,
        (__attribute__((address_space(3))) uint*)lbase, 16, 0, 0);
}

// ---------------------------------------------------------------------------
// f32 -> bf16 bulk convert (16B loads / 8B stores), exact-grid.
// ---------------------------------------------------------------------------
__global__ __launch_bounds__(256)
void cvt_bf16(const float* __restrict__ src, ushort* __restrict__ dst, int n4)
{
    const int i = blockIdx.x * 256 + threadIdx.x;
    if (i >= n4) return;
    const float4 v = ((const float4*)src)[i];
    ushort4 w;
    w.x = f2bf(v.x); w.y = f2bf(v.y); w.z = f2bf(v.z); w.w = f2bf(v.w);
    ((ushort4*)dst)[i] = w;
}

// ---------------------------------------------------------------------------
// RoPE table: tab[n][j] = (cos, sin) of n * 10000^(-j/32), j in [0,32).
// ---------------------------------------------------------------------------
__global__ __launch_bounds__(256)
void rope_tab_k(float2* __restrict__ tab)
{
    const int idx = blockIdx.x * 256 + threadIdx.x;   // 4096*32
    const int j = idx & 31;
    const int n = idx >> 5;
    const float invf = (float)pow(10000.0, -(double)j / 32.0);
    const float ang  = (float)n * invf;               // f32 (matches ref freqs)
    double s, c;
    sincos((double)ang, &s, &c);
    tab[idx] = make_float2((float)c, (float)s);
}

// ---------------------------------------------------------------------------
// QKV GEMM (bf16 in) + fused RoPE + layout:
//   t=0 (q): RoPE, *0.125*log2e (folds softmax's exp->exp2 conversion into
//            the Q scale so flash can use raw v_exp_f32), bf16 -> Qb[h][n][d]
//   t=1 (k): RoPE, bf16 -> Kb[h][n][d]
//   t=2 (v): bf16 -> Vp[h][d][64T + s], key-slot permuted (flash P order)
// Staging: global_load_lds width-16, linear LDS [128][64] (no pad — gload
// writes linearly; the 16-way frag-read bank conflict is the m97 tradeoff,
// net +69% on this structure per the measured ladder).
// ---------------------------------------------------------------------------
__global__ __launch_bounds__(256)
void gemm_qkv(const ushort* __restrict__ A, const ushort* __restrict__ B,
              const float2* __restrict__ tab,
              ushort* __restrict__ Qb, ushort* __restrict__ Kb,
              ushort* __restrict__ Vp)
{
    constexpr int BM = 128, BN = 128, BK = 64;
    __shared__ __attribute__((aligned(16))) ushort Ah[BM][BK];
    __shared__ __attribute__((aligned(16))) ushort Bh[BN][BK];

    const int t    = threadIdx.x;
    const int lane = t & 63;
    const int wv   = t >> 6;
    const int wm   = (wv >> 1) * 64;
    const int wn   = (wv & 1) * 64;
    const int m0   = blockIdx.y * BM;
    const int n0   = blockIdx.x * BN;

    f32x4 acc[4][4] = {};

    const int lrow = lane >> 3;        // 0..7  row within 8-row wave stripe
    const int lch  = (lane & 7) * 8;   // 16B chunk (ushort offset)

    for (int k0 = 0; k0 < DIM; k0 += BK) {
        #pragma unroll
        for (int i = 0; i < 4; ++i) {
            const int rb = i * 32 + wv * 8;          // wave-uniform row base
            gload16(&A[(size_t)(m0 + rb + lrow) * DIM + k0 + lch], &Ah[rb][0]);
            gload16(&B[(size_t)(n0 + rb + lrow) * DIM + k0 + lch], &Bh[rb][0]);
        }
        __syncthreads();   // drains vmcnt -> staged tile visible

        #pragma unroll
        for (int ks = 0; ks < BK; ks += 32) {
            const int koff = ks + ((lane >> 4) << 3);
            const int rs = lane & 15;
            bf16x8 af[4], bf[4];
            #pragma unroll
            for (int i = 0; i < 4; ++i) {
                af[i] = *(const bf16x8*)&Ah[wm + i * 16 + rs][koff];
                bf[i] = *(const bf16x8*)&Bh[wn + i * 16 + rs][koff];
            }
            #pragma unroll
            for (int i = 0; i < 4; ++i)
                #pragma unroll
                for (int j = 0; j < 4; ++j)
                    acc[i][j] = __builtin_amdgcn_mfma_f32_16x16x32_bf16(
                        af[i], bf[j], acc[i][j], 0, 0, 0);
        }
        __syncthreads();
    }

    const int rsel  = lane & 15;
    const int quad  = lane >> 4;
    const int rbase = m0 + wm + (quad << 2);
    const int c0    = n0 + wn;          // 64-aligned -> one (t,h) per wave
    const int tt    = c0 / DIM;
    const int h     = (c0 % DIM) >> 6;

    if (tt == 2) {
        // key kappa (within 64-tile) = 16i + 4quad + r -> slot 16quad + 4r + i
        const int T = (m0 + wm) >> 6;
        #pragma unroll
        for (int j = 0; j < 4; ++j) {
            const int d = rsel + 16 * j;
            ushort vv[16];
            #pragma unroll
            for (int r = 0; r < 4; ++r)
                #pragma unroll
                for (int i = 0; i < 4; ++i)
                    vv[4 * r + i] = f2bf(acc[i][j][r]);
            ushort* dst = &Vp[((size_t)h * HD + d) * SEQ + T * 64 + 16 * quad];
            *(float4*)&dst[0] = *(const float4*)&vv[0];
            *(float4*)&dst[8] = *(const float4*)&vv[8];
        }
    } else {
        ushort* dstb = (tt == 0 ? Qb : Kb) + (size_t)h * SEQ * HD;
        // 0.125 * log2(e): flash computes exp(S) as v_exp_f32(S') = 2^S'
        // with S' = QK * 0.125 * log2e — identical math to __expf's internal
        // expansion (0.125 is pow2, so the bf16 rounding grid is equivalent),
        // but the multiply rides the existing Q scale for free.
        const float qs = (tt == 0) ? 0.18033688011112042f : 1.0f;
        #pragma unroll
        for (int i = 0; i < 4; ++i)
            #pragma unroll
            for (int r = 0; r < 4; ++r) {
                const int n = rbase + i * 16 + r;
                #pragma unroll
                for (int j = 0; j < 2; ++j) {
                    const float a = acc[i][j][r];
                    const float b = acc[i][j + 2][r];
                    const float2 cs2 = tab[n * 32 + rsel + 16 * j];
                    dstb[(size_t)n * HD + rsel + 16 * j]      = f2bf((a * cs2.x - b * cs2.y) * qs);
                    dstb[(size_t)n * HD + rsel + 16 * j + 32] = f2bf((b * cs2.x + a * cs2.y) * qs);
                }
            }
    }
}

// ---------------------------------------------------------------------------
// MFMA flash attention — T1 XCD swizzle (r4, FETCH 70->22.6 MB) + T3 2-phase
// double-buffered K/V staging (ONE barrier per tile). Unchanged from r5
// (81.2 us, MfmaUtil 26.7, FETCH 15.5 MB).
// ---------------------------------------------------------------------------
__global__ __launch_bounds__(256, 3)
void flash_mfma(const ushort* __restrict__ Qb, const ushort* __restrict__ Kb,
                const ushort* __restrict__ Vp,
                float* __restrict__ Opart, float* __restrict__ lpart)
{
    __shared__ ushort Ks[2][64][68];   // [buf][key][d]
    __shared__ ushort Vs[2][64][68];   // [buf][d][slot]
    __shared__ ushort Pl[4][32][68];   // per-wave P, [row][slot]

    const int t    = threadIdx.x;
    const int lane = t & 63;
    const int wv   = t >> 6;
    const int rsel = lane & 15;
    const int quad = lane >> 4;

    // T1 XCD swizzle: flat dispatch id p -> (q-tile xq, group g=(h,part))
    // such that all 32 xq of a group share p%8 (= the XCD on round-robin HW).
    const int p  = blockIdx.x + 32 * (blockIdx.y + 12 * blockIdx.z);
    const int c  = p & 7;              // xcd slot
    const int r  = p >> 3;             // 0..191 position within xcd
    const int gi = r >> 5;             // 0..5   group index within xcd
    const int xq = r & 31;             // q-tile
    const int g  = gi * 8 + c;         // 0..47  (h,part) group
    const int h    = g % 12;
    const int part = g / 12;

    const int q0   = xq * 128 + wv * 32;
    const int Tbeg = (part * (SEQ / KSPLIT)) >> 6;
    const int Tend = Tbeg + (SEQ / KSPLIT) / 64;

    const int crow = t >> 2;           // 0..63 staging row
    const int ccol = (t & 3) * 16;     // 0/16/32/48 ushorts (2x16B per thread)

    // Q A-frags (persistent)
    bf16x8 aq[2][2];
    #pragma unroll
    for (int mi = 0; mi < 2; ++mi)
        #pragma unroll
        for (int ks = 0; ks < 2; ++ks)
            aq[mi][ks] = *(const bf16x8*)&Qb[((size_t)h * SEQ + q0 + 16 * mi + rsel) * HD
                                             + ks * 32 + quad * 8];

    f32x4 accO[2][4] = {};
    float lsum[2][4] = {};

    // prologue: stage tile Tbeg into buf 0
    {
        const ushort* ksrc = &Kb[((size_t)h * SEQ + Tbeg * 64 + crow) * HD + ccol];
        const float4 k0 = *(const float4*)&ksrc[0];
        const float4 k1 = *(const float4*)&ksrc[8];
        const ushort* vsrc = &Vp[((size_t)h * HD + crow) * SEQ + Tbeg * 64 + ccol];
        const float4 v0 = *(const float4*)&vsrc[0];
        const float4 v1 = *(const float4*)&vsrc[8];
        *(float4*)&Ks[0][crow][ccol]     = k0;
        *(float4*)&Ks[0][crow][ccol + 8] = k1;
        *(float4*)&Vs[0][crow][ccol]     = v0;
        *(float4*)&Vs[0][crow][ccol + 8] = v1;
    }
    __syncthreads();

    int cur = 0;
    for (int T = Tbeg; T < Tend; ++T) {
        // issue next-tile K/V loads (clamped on last iter: re-reads own tile,
        // L2-hot, harmless). In flight across the whole compute below.
        const int Tn = (T + 1 < Tend) ? T + 1 : T;
        const ushort* ksrc = &Kb[((size_t)h * SEQ + Tn * 64 + crow) * HD + ccol];
        const float4 kn0 = *(const float4*)&ksrc[0];
        const float4 kn1 = *(const float4*)&ksrc[8];
        const ushort* vsrc = &Vp[((size_t)h * HD + crow) * SEQ + Tn * 64 + ccol];
        const float4 vn0 = *(const float4*)&vsrc[0];
        const float4 vn1 = *(const float4*)&vsrc[8];

        // K and V B-frags from LDS buf[cur] (shared across both M-halves)
        bf16x8 bk[4][2], bv[4][2];
        #pragma unroll
        for (int n = 0; n < 4; ++n)
            #pragma unroll
            for (int ks = 0; ks < 2; ++ks) {
                bk[n][ks] = *(const bf16x8*)&Ks[cur][16 * n + rsel][32 * ks + quad * 8];
                bv[n][ks] = *(const bf16x8*)&Vs[cur][16 * n + rsel][32 * ks + quad * 8];
            }

        #pragma unroll
        for (int mi = 0; mi < 2; ++mi) {
            f32x4 accS[4] = {};
            #pragma unroll
            for (int ks = 0; ks < 2; ++ks)
                #pragma unroll
                for (int n = 0; n < 4; ++n)
                    accS[n] = __builtin_amdgcn_mfma_f32_16x16x32_bf16(
                        aq[mi][ks], bk[n][ks], accS[n], 0, 0, 0);

            // P = 2^S (log2e folded into Q); packed write,
            // slot s = 4rsel + n (key = 16n + rsel)
            #pragma unroll
            for (int r = 0; r < 4; ++r) {
                const float p0 = __builtin_amdgcn_exp2f(accS[0][r]);
                const float p1 = __builtin_amdgcn_exp2f(accS[1][r]);
                const float p2 = __builtin_amdgcn_exp2f(accS[2][r]);
                const float p3 = __builtin_amdgcn_exp2f(accS[3][r]);
                ushort4 pw;
                pw.x = f2bf_tw(p0); pw.y = f2bf_tw(p1);
                pw.z = f2bf_tw(p2); pw.w = f2bf_tw(p3);
                *(ushort4*)&Pl[wv][16 * mi + 4 * quad + r][4 * rsel] = pw;
                lsum[mi][r] += (p0 + p1) + (p2 + p3);
            }
        }

        // wave-private LDS RAW: drain writes before A-frag reads (once/tile)
        asm volatile("s_waitcnt lgkmcnt(0)" ::: "memory");

        #pragma unroll
        for (int mi = 0; mi < 2; ++mi) {
            bf16x8 ap[2];
            ap[0] = *(const bf16x8*)&Pl[wv][16 * mi + rsel][quad * 8];
            ap[1] = *(const bf16x8*)&Pl[wv][16 * mi + rsel][32 + quad * 8];
            #pragma unroll
            for (int ks = 0; ks < 2; ++ks)
                #pragma unroll
                for (int j = 0; j < 4; ++j)
                    accO[mi][j] = __builtin_amdgcn_mfma_f32_16x16x32_bf16(
                        ap[ks], bv[j][ks], accO[mi][j], 0, 0, 0);
        }

        // write staged tile T+1 into buf[cur^1] (compiler inserts the vmcnt
        // wait for the staged regs here — issued ~600cy ago, already landed;
        // cur^1 is dead since the barrier at end of tile T-1, so no race).
        *(float4*)&Ks[cur ^ 1][crow][ccol]     = kn0;
        *(float4*)&Ks[cur ^ 1][crow][ccol + 8] = kn1;
        *(float4*)&Vs[cur ^ 1][crow][ccol]     = vn0;
        *(float4*)&Vs[cur ^ 1][crow][ccol + 8] = vn1;
        __syncthreads();               // drains ds_writes, publishes buf[cur^1]
        cur ^= 1;
    }

    // one-time l reduction across rsel lanes
    #pragma unroll
    for (int mi = 0; mi < 2; ++mi)
        #pragma unroll
        for (int r = 0; r < 4; ++r) {
            float s = lsum[mi][r];
            s += __shfl_xor(s, 1);
            s += __shfl_xor(s, 2);
            s += __shfl_xor(s, 4);
            s += __shfl_xor(s, 8);
            lsum[mi][r] = s;
        }

    float* Ob = Opart + ((size_t)part * NHEADS + h) * SEQ * HD;
    float* lb = lpart + ((size_t)part * NHEADS + h) * SEQ;
    #pragma unroll
    for (int mi = 0; mi < 2; ++mi)
        #pragma unroll
        for (int r = 0; r < 4; ++r) {
            const int n = q0 + 16 * mi + 4 * quad + r;
            #pragma unroll
            for (int j = 0; j < 4; ++j)
                Ob[(size_t)n * HD + 16 * j + rsel] = accO[mi][j][r];
            if (rsel == 0) lb[n] = lsum[mi][r];
        }
}

// ---------------------------------------------------------------------------
// Split-K merge: AO[n][h*64+d] = (sum_p Opart) / (sum_p l), bf16.
// ---------------------------------------------------------------------------
__global__ __launch_bounds__(256)
void merge_k(const float* __restrict__ Opart, const float* __restrict__ lpart,
             ushort* __restrict__ AO)
{
    const int idx = blockIdx.x * 256 + threadIdx.x;
    const int dg = idx & 15;
    const int n  = (idx >> 4) & (SEQ - 1);
    const int h  = idx >> 16;

    float4 o = make_float4(0.f, 0.f, 0.f, 0.f);
    float l = 0.f;
    #pragma unroll
    for (int p = 0; p < KSPLIT; ++p) {
        const float4 v = *(const float4*)&Opart[(((size_t)p * NHEADS + h) * SEQ + n) * HD + dg * 4];
        o.x += v.x; o.y += v.y; o.z += v.z; o.w += v.w;
        l += lpart[((size_t)p * NHEADS + h) * SEQ + n];
    }
    const float inv = 1.f / l;
    ushort4 w;
    w.x = f2bf(o.x * inv); w.y = f2bf(o.y * inv);
    w.z = f2bf(o.z * inv); w.w = f2bf(o.w * inv);
    *(ushort4*)&AO[(size_t)n * DIM + h * HD + dg * 4] = w;
}

// ---------------------------------------------------------------------------
// Proj GEMM: out = attnout(bf16) @ proj_wb(bf16)^T + proj_b(f32), f32 out.
// Staging: global_load_lds width-16 (same as gemm_qkv).
// ---------------------------------------------------------------------------
__global__ __launch_bounds__(256)
void gemm_proj(const ushort* __restrict__ A, const ushort* __restrict__ B,
               const float* __restrict__ bias, float* __restrict__ out)
{
    constexpr int BM = 128, BN = 128, BK = 64;
    __shared__ __attribute__((aligned(16))) ushort As[BM][BK];
    __shared__ __attribute__((aligned(16))) ushort Bs[BN][BK];

    const int t    = threadIdx.x;
    const int lane = t & 63;
    const int wv   = t >> 6;
    const int wm   = (wv >> 1) * 64;
    const int wn   = (wv & 1) * 64;
    const int m0   = blockIdx.y * BM;
    const int n0   = blockIdx.x * BN;

    f32x4 acc[4][4] = {};

    const int lrow = lane >> 3;
    const int lch  = (lane & 7) * 8;

    for (int k0 = 0; k0 < DIM; k0 += BK) {
        #pragma unroll
        for (int i = 0; i < 4; ++i) {
            const int rb = i * 32 + wv * 8;
            gload16(&A[(size_t)(m0 + rb + lrow) * DIM + k0 + lch], &As[rb][0]);
            gload16(&B[(size_t)(n0 + rb + lrow) * DIM + k0 + lch], &Bs[rb][0]);
        }
        __syncthreads();

        #pragma unroll
        for (int ks = 0; ks < BK; ks += 32) {
            const int koff = ks + ((lane >> 4) << 3);
            const int rs = lane & 15;
            bf16x8 af[4], bf[4];
            #pragma unroll
            for (int i = 0; i < 4; ++i) {
                af[i] = *(const bf16x8*)&As[wm + i * 16 + rs][koff];
                bf[i] = *(const bf16x8*)&Bs[wn + i * 16 + rs][koff];
            }
            #pragma unroll
            for (int i = 0; i < 4; ++i)
                #pragma unroll
                for (int j = 0; j < 4; ++j)
                    acc[i][j] = __builtin_amdgcn_mfma_f32_16x16x32_bf16(
                        af[i], bf[j], acc[i][j], 0, 0, 0);
        }
        __syncthreads();
    }

    const int rbase = m0 + wm + ((lane >> 4) << 2);
    const int cbase = n0 + wn + (lane & 15);

    #pragma unroll
    for (int j = 0; j < 4; ++j) {
        const int col = cbase + j * 16;
        const float bv = bias[col];
        #pragma unroll
        for (int i = 0; i < 4; ++i) {
            const int row0 = rbase + i * 16;
            #pragma unroll
            for (int r = 0; r < 4; ++r)
                out[(size_t)(row0 + r) * DIM + col] = acc[i][j][r] + bv;
        }
    }
}

// ---------------------------------------------------------------------------
extern "C" void kernel_launch(void* const* d_in, const int* in_sizes, int n_in,
                              void* d_out, int out_size, void* d_ws, size_t ws_size,
                              hipStream_t stream)
{
    const float* x      = (const float*)d_in[0];
    const float* qkv_w  = (const float*)d_in[1];
    const float* proj_w = (const float*)d_in[2];
    const float* proj_b = (const float*)d_in[3];

    const size_t headsz = (size_t)NHEADS * SEQ * HD;       // 3,145,728
    char* p = (char*)d_ws;
    ushort* Qb    = (ushort*)p;                 p += headsz * 2;
    ushort* Kb    = (ushort*)p;                 p += headsz * 2;
    ushort* Vp    = (ushort*)p;                 p += headsz * 2;
    ushort* AO    = (ushort*)p;                 p += (size_t)SEQ * DIM * 2;
    float*  Opart = (float*)p;                  p += (size_t)KSPLIT * headsz * 4;
    float*  lpart = (float*)p;                  p += (size_t)KSPLIT * NHEADS * SEQ * 4;
    float2* tab   = (float2*)p;                 p += (size_t)SEQ * 32 * sizeof(float2);
    ushort* xb    = (ushort*)p;                 p += (size_t)SEQ * DIM * 2;
    ushort* qwb   = (ushort*)p;                 p += (size_t)3 * DIM * DIM * 2;
    ushort* pwb   = (ushort*)p;
    float*  out   = (float*)d_out;

    rope_tab_k<<<(SEQ * 32) / 256, 256, 0, stream>>>(tab);
    cvt_bf16<<<(SEQ * DIM / 4) / 256, 256, 0, stream>>>(x, xb, SEQ * DIM / 4);
    cvt_bf16<<<(3 * DIM * DIM / 4) / 256, 256, 0, stream>>>(qkv_w, qwb, 3 * DIM * DIM / 4);
    cvt_bf16<<<(DIM * DIM / 4) / 256, 256, 0, stream>>>(proj_w, pwb, DIM * DIM / 4);

    gemm_qkv<<<dim3(3 * DIM / 128, SEQ / 128), 256, 0, stream>>>(
        xb, qwb, tab, Qb, Kb, Vp);

    flash_mfma<<<dim3(SEQ / 128, NHEADS, KSPLIT), 256, 0, stream>>>(
        Qb, Kb, Vp, Opart, lpart);

    merge_k<<<(NHEADS * SEQ * 16) / 256, 256, 0, stream>>>(Opart, lpart, AO);

    gemm_proj<<<dim3(DIM / 128, SEQ / 128), 256, 0, stream>>>(
        AO, pwb, proj_b, out);
}

// Round 7
// 211.218 us; speedup vs baseline: 1.0294x; 1.0294x over previous
//
#include <hip/hip_runtime.h>
#include <hip/hip_bf16.h>
#include <math.h>

#define DIM 768
#define NHEADS 12
#define HD 64
#define SEQ 4096
#define KSPLIT 2

typedef __bf16 bf16x8 __attribute__((ext_vector_type(8)));
typedef float f32x4 __attribute__((ext_vector_type(4)));

// Native bf16 convert (RNE) — used outside flash.
__device__ inline ushort f2bf(float f) {
    __bf16 b = (__bf16)f;
    union { __bf16 b; ushort u; } v; v.b = b;
    return v.u;
}

// Manual RNE twiddle — used inside flash (unbiased RNE REQUIRED:
// v_cvt_pk_bf16_f32 biased P downward, failed absmax 4.3e-2 in round 1).
__device__ inline ushort f2bf_tw(float f) {
    union { float f; uint u; } v; v.f = f;
    uint r = v.u + 0x7FFF + ((v.u >> 16) & 1);
    return (ushort)(r >> 16);
}

// global -> LDS direct copy, 16B per lane. LDS dest is WAVE-UNIFORM base
// (hw adds lane*16); global src is per-lane.
__device__ inline void gload16(const ushort* gsrc, ushort* lbase) {
    __builtin_amdgcn_global_load_lds(
        (const __attribute__((address_space(1))) uint*)gsrc,
        (__attribute__((address_space(3))) uint*)lbase, 16, 0, 0);
}

// ---------------------------------------------------------------------------
// Fused prologue (saves 3 dispatches): block-range dispatch over
//   [0,3072)    : x f32 -> bf16            (4096*768 /4 /256)
//   [3072,4800) : qkv_w f32 -> bf16        (3*768*768 /4 /256)
//   [4800,5376) : proj_w f32 -> bf16       (768*768 /4 /256)
//   [5376,5888) : RoPE table tab[n][j]     (4096*32 /256)
// ---------------------------------------------------------------------------
__global__ __launch_bounds__(256)
void prep(const float* __restrict__ x, const float* __restrict__ qkv_w,
          const float* __restrict__ proj_w,
          ushort* __restrict__ xb, ushort* __restrict__ qwb,
          ushort* __restrict__ pwb, float2* __restrict__ tab)
{
    const int b = blockIdx.x;
    if (b < 5376) {
        const float* src; ushort* dst; int i;
        if (b < 3072)      { src = x;      dst = xb;  i = b * 256 + threadIdx.x; }
        else if (b < 4800) { src = qkv_w;  dst = qwb; i = (b - 3072) * 256 + threadIdx.x; }
        else               { src = proj_w; dst = pwb; i = (b - 4800) * 256 + threadIdx.x; }
        const float4 v = ((const float4*)src)[i];
        ushort4 w;
        w.x = f2bf(v.x); w.y = f2bf(v.y); w.z = f2bf(v.z); w.w = f2bf(v.w);
        ((ushort4*)dst)[i] = w;
    } else {
        const int idx = (b - 5376) * 256 + threadIdx.x;   // 4096*32
        const int j = idx & 31;
        const int n = idx >> 5;
        const float invf = (float)pow(10000.0, -(double)j / 32.0);
        const float ang  = (float)n * invf;               // f32 (matches ref freqs)
        double s, c;
        sincos((double)ang, &s, &c);
        tab[idx] = make_float2((float)c, (float)s);
    }
}

// ---------------------------------------------------------------------------
// QKV GEMM (bf16 in) + fused RoPE + layout:
//   t=0 (q): RoPE, *0.125*log2e (exp->exp2 fold), bf16 -> Qb[h][n][d]
//   t=1 (k): RoPE, bf16 -> Kb[h][n][d]
//   t=2 (v): bf16 -> Vp[h][d][64T + s], key-slot permuted (flash P order)
// Staging: global_load_lds width-16, linear LDS [128][64].
// ---------------------------------------------------------------------------
__global__ __launch_bounds__(256)
void gemm_qkv(const ushort* __restrict__ A, const ushort* __restrict__ B,
              const float2* __restrict__ tab,
              ushort* __restrict__ Qb, ushort* __restrict__ Kb,
              ushort* __restrict__ Vp)
{
    constexpr int BM = 128, BN = 128, BK = 64;
    __shared__ __attribute__((aligned(16))) ushort Ah[BM][BK];
    __shared__ __attribute__((aligned(16))) ushort Bh[BN][BK];

    const int t    = threadIdx.x;
    const int lane = t & 63;
    const int wv   = t >> 6;
    const int wm   = (wv >> 1) * 64;
    const int wn   = (wv & 1) * 64;
    const int m0   = blockIdx.y * BM;
    const int n0   = blockIdx.x * BN;

    f32x4 acc[4][4] = {};

    const int lrow = lane >> 3;        // 0..7  row within 8-row wave stripe
    const int lch  = (lane & 7) * 8;   // 16B chunk (ushort offset)

    for (int k0 = 0; k0 < DIM; k0 += BK) {
        #pragma unroll
        for (int i = 0; i < 4; ++i) {
            const int rb = i * 32 + wv * 8;          // wave-uniform row base
            gload16(&A[(size_t)(m0 + rb + lrow) * DIM + k0 + lch], &Ah[rb][0]);
            gload16(&B[(size_t)(n0 + rb + lrow) * DIM + k0 + lch], &Bh[rb][0]);
        }
        __syncthreads();   // drains vmcnt -> staged tile visible

        #pragma unroll
        for (int ks = 0; ks < BK; ks += 32) {
            const int koff = ks + ((lane >> 4) << 3);
            const int rs = lane & 15;
            bf16x8 af[4], bf[4];
            #pragma unroll
            for (int i = 0; i < 4; ++i) {
                af[i] = *(const bf16x8*)&Ah[wm + i * 16 + rs][koff];
                bf[i] = *(const bf16x8*)&Bh[wn + i * 16 + rs][koff];
            }
            #pragma unroll
            for (int i = 0; i < 4; ++i)
                #pragma unroll
                for (int j = 0; j < 4; ++j)
                    acc[i][j] = __builtin_amdgcn_mfma_f32_16x16x32_bf16(
                        af[i], bf[j], acc[i][j], 0, 0, 0);
        }
        __syncthreads();
    }

    const int rsel  = lane & 15;
    const int quad  = lane >> 4;
    const int rbase = m0 + wm + (quad << 2);
    const int c0    = n0 + wn;          // 64-aligned -> one (t,h) per wave
    const int tt    = c0 / DIM;
    const int h     = (c0 % DIM) >> 6;

    if (tt == 2) {
        // key kappa (within 64-tile) = 16i + 4quad + r -> slot 16quad + 4r + i
        const int T = (m0 + wm) >> 6;
        #pragma unroll
        for (int j = 0; j < 4; ++j) {
            const int d = rsel + 16 * j;
            ushort vv[16];
            #pragma unroll
            for (int r = 0; r < 4; ++r)
                #pragma unroll
                for (int i = 0; i < 4; ++i)
                    vv[4 * r + i] = f2bf(acc[i][j][r]);
            ushort* dst = &Vp[((size_t)h * HD + d) * SEQ + T * 64 + 16 * quad];
            *(float4*)&dst[0] = *(const float4*)&vv[0];
            *(float4*)&dst[8] = *(const float4*)&vv[8];
        }
    } else {
        ushort* dstb = (tt == 0 ? Qb : Kb) + (size_t)h * SEQ * HD;
        // 0.125 * log2(e): flash computes exp(S) via v_exp_f32 (2^S').
        const float qs = (tt == 0) ? 0.18033688011112042f : 1.0f;
        #pragma unroll
        for (int i = 0; i < 4; ++i)
            #pragma unroll
            for (int r = 0; r < 4; ++r) {
                const int n = rbase + i * 16 + r;
                #pragma unroll
                for (int j = 0; j < 2; ++j) {
                    const float a = acc[i][j][r];
                    const float b = acc[i][j + 2][r];
                    const float2 cs2 = tab[n * 32 + rsel + 16 * j];
                    dstb[(size_t)n * HD + rsel + 16 * j]      = f2bf((a * cs2.x - b * cs2.y) * qs);
                    dstb[(size_t)n * HD + rsel + 16 * j + 32] = f2bf((b * cs2.x + a * cs2.y) * qs);
                }
            }
    }
}

// ---------------------------------------------------------------------------
// MFMA flash attention — T1 XCD swizzle + T3 2-phase dbuf (r5: 81 us).
// KSPLIT=2: grid 768 blocks = exactly 3/CU x 256 CU (one residency round,
// zero tail); Opart/lpart write traffic halves (50->25 MB).
// Swizzle re-derived for 24 (h,part) groups: g=(r>>5)*8+(p&7), g in [0,24)
// bijective; per-XCD live set 3 groups x 512 KB = 1.5 MB < 4 MB L2.
// ---------------------------------------------------------------------------
__global__ __launch_bounds__(256, 3)
void flash_mfma(const ushort* __restrict__ Qb, const ushort* __restrict__ Kb,
                const ushort* __restrict__ Vp,
                float* __restrict__ Opart, float* __restrict__ lpart)
{
    __shared__ ushort Ks[2][64][68];   // [buf][key][d]
    __shared__ ushort Vs[2][64][68];   // [buf][d][slot]
    __shared__ ushort Pl[4][32][68];   // per-wave P, [row][slot]

    const int t    = threadIdx.x;
    const int lane = t & 63;
    const int wv   = t >> 6;
    const int rsel = lane & 15;
    const int quad = lane >> 4;

    // T1 XCD swizzle: flat dispatch id p -> (q-tile xq, group g=(h,part))
    // such that all 32 xq of a group share p%8 (= the XCD on round-robin HW).
    const int p  = blockIdx.x + 32 * (blockIdx.y + 12 * blockIdx.z);
    const int c  = p & 7;              // xcd slot
    const int r  = p >> 3;             // 0..95 position within xcd
    const int gi = r >> 5;             // 0..2  group index within xcd
    const int xq = r & 31;             // q-tile
    const int g  = gi * 8 + c;         // 0..23 (h,part) group
    const int h    = g % 12;
    const int part = g / 12;

    const int q0   = xq * 128 + wv * 32;
    const int Tbeg = (part * (SEQ / KSPLIT)) >> 6;
    const int Tend = Tbeg + (SEQ / KSPLIT) / 64;

    const int crow = t >> 2;           // 0..63 staging row
    const int ccol = (t & 3) * 16;     // 0/16/32/48 ushorts (2x16B per thread)

    // Q A-frags (persistent)
    bf16x8 aq[2][2];
    #pragma unroll
    for (int mi = 0; mi < 2; ++mi)
        #pragma unroll
        for (int ks = 0; ks < 2; ++ks)
            aq[mi][ks] = *(const bf16x8*)&Qb[((size_t)h * SEQ + q0 + 16 * mi + rsel) * HD
                                             + ks * 32 + quad * 8];

    f32x4 accO[2][4] = {};
    float lsum[2][4] = {};

    // prologue: stage tile Tbeg into buf 0
    {
        const ushort* ksrc = &Kb[((size_t)h * SEQ + Tbeg * 64 + crow) * HD + ccol];
        const float4 k0 = *(const float4*)&ksrc[0];
        const float4 k1 = *(const float4*)&ksrc[8];
        const ushort* vsrc = &Vp[((size_t)h * HD + crow) * SEQ + Tbeg * 64 + ccol];
        const float4 v0 = *(const float4*)&vsrc[0];
        const float4 v1 = *(const float4*)&vsrc[8];
        *(float4*)&Ks[0][crow][ccol]     = k0;
        *(float4*)&Ks[0][crow][ccol + 8] = k1;
        *(float4*)&Vs[0][crow][ccol]     = v0;
        *(float4*)&Vs[0][crow][ccol + 8] = v1;
    }
    __syncthreads();

    int cur = 0;
    for (int T = Tbeg; T < Tend; ++T) {
        // issue next-tile K/V loads (clamped on last iter: re-reads own tile,
        // L2-hot, harmless). In flight across the whole compute below.
        const int Tn = (T + 1 < Tend) ? T + 1 : T;
        const ushort* ksrc = &Kb[((size_t)h * SEQ + Tn * 64 + crow) * HD + ccol];
        const float4 kn0 = *(const float4*)&ksrc[0];
        const float4 kn1 = *(const float4*)&ksrc[8];
        const ushort* vsrc = &Vp[((size_t)h * HD + crow) * SEQ + Tn * 64 + ccol];
        const float4 vn0 = *(const float4*)&vsrc[0];
        const float4 vn1 = *(const float4*)&vsrc[8];

        // K and V B-frags from LDS buf[cur] (shared across both M-halves)
        bf16x8 bk[4][2], bv[4][2];
        #pragma unroll
        for (int n = 0; n < 4; ++n)
            #pragma unroll
            for (int ks = 0; ks < 2; ++ks) {
                bk[n][ks] = *(const bf16x8*)&Ks[cur][16 * n + rsel][32 * ks + quad * 8];
                bv[n][ks] = *(const bf16x8*)&Vs[cur][16 * n + rsel][32 * ks + quad * 8];
            }

        #pragma unroll
        for (int mi = 0; mi < 2; ++mi) {
            f32x4 accS[4] = {};
            #pragma unroll
            for (int ks = 0; ks < 2; ++ks)
                #pragma unroll
                for (int n = 0; n < 4; ++n)
                    accS[n] = __builtin_amdgcn_mfma_f32_16x16x32_bf16(
                        aq[mi][ks], bk[n][ks], accS[n], 0, 0, 0);

            // P = 2^S (log2e folded into Q); packed write,
            // slot s = 4rsel + n (key = 16n + rsel)
            #pragma unroll
            for (int r = 0; r < 4; ++r) {
                const float p0 = __builtin_amdgcn_exp2f(accS[0][r]);
                const float p1 = __builtin_amdgcn_exp2f(accS[1][r]);
                const float p2 = __builtin_amdgcn_exp2f(accS[2][r]);
                const float p3 = __builtin_amdgcn_exp2f(accS[3][r]);
                ushort4 pw;
                pw.x = f2bf_tw(p0); pw.y = f2bf_tw(p1);
                pw.z = f2bf_tw(p2); pw.w = f2bf_tw(p3);
                *(ushort4*)&Pl[wv][16 * mi + 4 * quad + r][4 * rsel] = pw;
                lsum[mi][r] += (p0 + p1) + (p2 + p3);
            }
        }

        // wave-private LDS RAW: drain writes before A-frag reads (once/tile)
        asm volatile("s_waitcnt lgkmcnt(0)" ::: "memory");

        #pragma unroll
        for (int mi = 0; mi < 2; ++mi) {
            bf16x8 ap[2];
            ap[0] = *(const bf16x8*)&Pl[wv][16 * mi + rsel][quad * 8];
            ap[1] = *(const bf16x8*)&Pl[wv][16 * mi + rsel][32 + quad * 8];
            #pragma unroll
            for (int ks = 0; ks < 2; ++ks)
                #pragma unroll
                for (int j = 0; j < 4; ++j)
                    accO[mi][j] = __builtin_amdgcn_mfma_f32_16x16x32_bf16(
                        ap[ks], bv[j][ks], accO[mi][j], 0, 0, 0);
        }

        // write staged tile T+1 into buf[cur^1] (vmcnt wait lands here —
        // loads issued ~600cy ago; cur^1 dead since prior-tile barrier).
        *(float4*)&Ks[cur ^ 1][crow][ccol]     = kn0;
        *(float4*)&Ks[cur ^ 1][crow][ccol + 8] = kn1;
        *(float4*)&Vs[cur ^ 1][crow][ccol]     = vn0;
        *(float4*)&Vs[cur ^ 1][crow][ccol + 8] = vn1;
        __syncthreads();               // drains ds_writes, publishes buf[cur^1]
        cur ^= 1;
    }

    // one-time l reduction across rsel lanes
    #pragma unroll
    for (int mi = 0; mi < 2; ++mi)
        #pragma unroll
        for (int r = 0; r < 4; ++r) {
            float s = lsum[mi][r];
            s += __shfl_xor(s, 1);
            s += __shfl_xor(s, 2);
            s += __shfl_xor(s, 4);
            s += __shfl_xor(s, 8);
            lsum[mi][r] = s;
        }

    float* Ob = Opart + ((size_t)part * NHEADS + h) * SEQ * HD;
    float* lb = lpart + ((size_t)part * NHEADS + h) * SEQ;
    #pragma unroll
    for (int mi = 0; mi < 2; ++mi)
        #pragma unroll
        for (int r = 0; r < 4; ++r) {
            const int n = q0 + 16 * mi + 4 * quad + r;
            #pragma unroll
            for (int j = 0; j < 4; ++j)
                Ob[(size_t)n * HD + 16 * j + rsel] = accO[mi][j][r];
            if (rsel == 0) lb[n] = lsum[mi][r];
        }
}

// ---------------------------------------------------------------------------
// Split-K merge: AO[n][h*64+d] = (sum_p Opart) / (sum_p l), bf16.
// ---------------------------------------------------------------------------
__global__ __launch_bounds__(256)
void merge_k(const float* __restrict__ Opart, const float* __restrict__ lpart,
             ushort* __restrict__ AO)
{
    const int idx = blockIdx.x * 256 + threadIdx.x;
    const int dg = idx & 15;
    const int n  = (idx >> 4) & (SEQ - 1);
    const int h  = idx >> 16;

    float4 o = make_float4(0.f, 0.f, 0.f, 0.f);
    float l = 0.f;
    #pragma unroll
    for (int p = 0; p < KSPLIT; ++p) {
        const float4 v = *(const float4*)&Opart[(((size_t)p * NHEADS + h) * SEQ + n) * HD + dg * 4];
        o.x += v.x; o.y += v.y; o.z += v.z; o.w += v.w;
        l += lpart[((size_t)p * NHEADS + h) * SEQ + n];
    }
    const float inv = 1.f / l;
    ushort4 w;
    w.x = f2bf(o.x * inv); w.y = f2bf(o.y * inv);
    w.z = f2bf(o.z * inv); w.w = f2bf(o.w * inv);
    *(ushort4*)&AO[(size_t)n * DIM + h * HD + dg * 4] = w;
}

// ---------------------------------------------------------------------------
// Proj GEMM: out = attnout(bf16) @ proj_wb(bf16)^T + proj_b(f32), f32 out.
// Staging: global_load_lds width-16 (same as gemm_qkv).
// ---------------------------------------------------------------------------
__global__ __launch_bounds__(256)
void gemm_proj(const ushort* __restrict__ A, const ushort* __restrict__ B,
               const float* __restrict__ bias, float* __restrict__ out)
{
    constexpr int BM = 128, BN = 128, BK = 64;
    __shared__ __attribute__((aligned(16))) ushort As[BM][BK];
    __shared__ __attribute__((aligned(16))) ushort Bs[BN][BK];

    const int t    = threadIdx.x;
    const int lane = t & 63;
    const int wv   = t >> 6;
    const int wm   = (wv >> 1) * 64;
    const int wn   = (wv & 1) * 64;
    const int m0   = blockIdx.y * BM;
    const int n0   = blockIdx.x * BN;

    f32x4 acc[4][4] = {};

    const int lrow = lane >> 3;
    const int lch  = (lane & 7) * 8;

    for (int k0 = 0; k0 < DIM; k0 += BK) {
        #pragma unroll
        for (int i = 0; i < 4; ++i) {
            const int rb = i * 32 + wv * 8;
            gload16(&A[(size_t)(m0 + rb + lrow) * DIM + k0 + lch], &As[rb][0]);
            gload16(&B[(size_t)(n0 + rb + lrow) * DIM + k0 + lch], &Bs[rb][0]);
        }
        __syncthreads();

        #pragma unroll
        for (int ks = 0; ks < BK; ks += 32) {
            const int koff = ks + ((lane >> 4) << 3);
            const int rs = lane & 15;
            bf16x8 af[4], bf[4];
            #pragma unroll
            for (int i = 0; i < 4; ++i) {
                af[i] = *(const bf16x8*)&As[wm + i * 16 + rs][koff];
                bf[i] = *(const bf16x8*)&Bs[wn + i * 16 + rs][koff];
            }
            #pragma unroll
            for (int i = 0; i < 4; ++i)
                #pragma unroll
                for (int j = 0; j < 4; ++j)
                    acc[i][j] = __builtin_amdgcn_mfma_f32_16x16x32_bf16(
                        af[i], bf[j], acc[i][j], 0, 0, 0);
        }
        __syncthreads();
    }

    const int rbase = m0 + wm + ((lane >> 4) << 2);
    const int cbase = n0 + wn + (lane & 15);

    #pragma unroll
    for (int j = 0; j < 4; ++j) {
        const int col = cbase + j * 16;
        const float bv = bias[col];
        #pragma unroll
        for (int i = 0; i < 4; ++i) {
            const int row0 = rbase + i * 16;
            #pragma unroll
            for (int r = 0; r < 4; ++r)
                out[(size_t)(row0 + r) * DIM + col] = acc[i][j][r] + bv;
        }
    }
}

// ---------------------------------------------------------------------------
extern "C" void kernel_launch(void* const* d_in, const int* in_sizes, int n_in,
                              void* d_out, int out_size, void* d_ws, size_t ws_size,
                              hipStream_t stream)
{
    const float* x      = (const float*)d_in[0];
    const float* qkv_w  = (const float*)d_in[1];
    const float* proj_w = (const float*)d_in[2];
    const float* proj_b = (const float*)d_in[3];

    const size_t headsz = (size_t)NHEADS * SEQ * HD;       // 3,145,728
    char* p = (char*)d_ws;
    ushort* Qb    = (ushort*)p;                 p += headsz * 2;
    ushort* Kb    = (ushort*)p;                 p += headsz * 2;
    ushort* Vp    = (ushort*)p;                 p += headsz * 2;
    ushort* AO    = (ushort*)p;                 p += (size_t)SEQ * DIM * 2;
    float*  Opart = (float*)p;                  p += (size_t)KSPLIT * headsz * 4;
    float*  lpart = (float*)p;                  p += (size_t)KSPLIT * NHEADS * SEQ * 4;
    float2* tab   = (float2*)p;                 p += (size_t)SEQ * 32 * sizeof(float2);
    ushort* xb    = (ushort*)p;                 p += (size_t)SEQ * DIM * 2;
    ushort* qwb   = (ushort*)p;                 p += (size_t)3 * DIM * DIM * 2;
    ushort* pwb   = (ushort*)p;
    float*  out   = (float*)d_out;

    prep<<<5888, 256, 0, stream>>>(x, qkv_w, proj_w, xb, qwb, pwb, tab);

    gemm_qkv<<<dim3(3 * DIM / 128, SEQ / 128), 256, 0, stream>>>(
        xb, qwb, tab, Qb, Kb, Vp);

    flash_mfma<<<dim3(SEQ / 128, NHEADS, KSPLIT), 256, 0, stream>>>(
        Qb, Kb, Vp, Opart, lpart);

    merge_k<<<(NHEADS * SEQ * 16) / 256, 256, 0, stream>>>(Opart, lpart, AO);

    gemm_proj<<<dim3(DIM / 128, SEQ / 128), 256, 0, stream>>>(
        AO, pwb, proj_b, out);
}

// Round 8
// 202.364 us; speedup vs baseline: 1.0745x; 1.0438x over previous
//
#include <hip/hip_runtime.h>
#include <hip/hip_bf16.h>
#include <math.h>

#define DIM 768
#define NHEADS 12
#define HD 64
#define SEQ 4096
#define KSPLIT 2

typedef __bf16 bf16x8 __attribute__((ext_vector_type(8)));
typedef float f32x4 __attribute__((ext_vector_type(4)));

// Native bf16 convert (RNE) — used outside flash.
__device__ inline ushort f2bf(float f) {
    __bf16 b = (__bf16)f;
    union { __bf16 b; ushort u; } v; v.b = b;
    return v.u;
}

// Manual RNE twiddle — used inside flash (unbiased RNE REQUIRED:
// v_cvt_pk_bf16_f32 biased P downward, failed absmax 4.3e-2 in round 1).
__device__ inline ushort f2bf_tw(float f) {
    union { float f; uint u; } v; v.f = f;
    uint r = v.u + 0x7FFF + ((v.u >> 16) & 1);
    return (ushort)(r >> 16);
}

// global -> LDS direct copy, 16B per lane. LDS dest is WAVE-UNIFORM base
// (hw adds lane*16); global src is per-lane.
__device__ inline void gload16(const ushort* gsrc, ushort* lbase) {
    __builtin_amdgcn_global_load_lds(
        (const __attribute__((address_space(1))) uint*)gsrc,
        (__attribute__((address_space(3))) uint*)lbase, 16, 0, 0);
}

// ---------------------------------------------------------------------------
// Fused prologue: block-range dispatch over
//   [0,3072)    : x f32 -> bf16            (4096*768 /4 /256)
//   [3072,4800) : qkv_w f32 -> bf16        (3*768*768 /4 /256)
//   [4800,5376) : proj_w f32 -> bf16       (768*768 /4 /256)
//   [5376,5888) : RoPE table tab[n][j]     (4096*32 /256)
// ---------------------------------------------------------------------------
__global__ __launch_bounds__(256)
void prep(const float* __restrict__ x, const float* __restrict__ qkv_w,
          const float* __restrict__ proj_w,
          ushort* __restrict__ xb, ushort* __restrict__ qwb,
          ushort* __restrict__ pwb, float2* __restrict__ tab)
{
    const int b = blockIdx.x;
    if (b < 5376) {
        const float* src; ushort* dst; int i;
        if (b < 3072)      { src = x;      dst = xb;  i = b * 256 + threadIdx.x; }
        else if (b < 4800) { src = qkv_w;  dst = qwb; i = (b - 3072) * 256 + threadIdx.x; }
        else               { src = proj_w; dst = pwb; i = (b - 4800) * 256 + threadIdx.x; }
        const float4 v = ((const float4*)src)[i];
        ushort4 w;
        w.x = f2bf(v.x); w.y = f2bf(v.y); w.z = f2bf(v.z); w.w = f2bf(v.w);
        ((ushort4*)dst)[i] = w;
    } else {
        const int idx = (b - 5376) * 256 + threadIdx.x;   // 4096*32
        const int j = idx & 31;
        const int n = idx >> 5;
        const float invf = (float)pow(10000.0, -(double)j / 32.0);
        const float ang  = (float)n * invf;               // f32 (matches ref freqs)
        double s, c;
        sincos((double)ang, &s, &c);
        tab[idx] = make_float2((float)c, (float)s);
    }
}

// ---------------------------------------------------------------------------
// QKV GEMM (bf16 in) + fused RoPE + layout. T3 1-barrier double-buffered
// K-loop: issue tile k+1 gloads into buf^1, compute tile k from buf, ONE
// __syncthreads per step (its vmcnt drain lands after ~800cy of ds_read+MFMA
// -> staging latency hidden; was: 2 barriers + fully-exposed drain).
// Buf^1 write-safety: its last reads were ordered by the PREVIOUS barrier.
// LDS 64 KB -> 2 blocks/CU.
//   t=0 (q): RoPE, *0.125*log2e (exp->exp2 fold), bf16 -> Qb[h][n][d]
//   t=1 (k): RoPE, bf16 -> Kb[h][n][d]
//   t=2 (v): bf16 -> Vp[h][d][64T + s], key-slot permuted (flash P order)
// ---------------------------------------------------------------------------
__global__ __launch_bounds__(256)
void gemm_qkv(const ushort* __restrict__ A, const ushort* __restrict__ B,
              const float2* __restrict__ tab,
              ushort* __restrict__ Qb, ushort* __restrict__ Kb,
              ushort* __restrict__ Vp)
{
    constexpr int BM = 128, BN = 128, BK = 64;
    __shared__ __attribute__((aligned(16))) ushort Ah[2][BM][BK];
    __shared__ __attribute__((aligned(16))) ushort Bh[2][BN][BK];

    const int t    = threadIdx.x;
    const int lane = t & 63;
    const int wv   = t >> 6;
    const int wm   = (wv >> 1) * 64;
    const int wn   = (wv & 1) * 64;
    const int m0   = blockIdx.y * BM;
    const int n0   = blockIdx.x * BN;

    f32x4 acc[4][4] = {};

    const int lrow = lane >> 3;        // 0..7  row within 8-row wave stripe
    const int lch  = (lane & 7) * 8;   // 16B chunk (ushort offset)

    // prologue: stage k0=0 into buf 0
    #pragma unroll
    for (int i = 0; i < 4; ++i) {
        const int rb = i * 32 + wv * 8;          // wave-uniform row base
        gload16(&A[(size_t)(m0 + rb + lrow) * DIM + lch], &Ah[0][rb][0]);
        gload16(&B[(size_t)(n0 + rb + lrow) * DIM + lch], &Bh[0][rb][0]);
    }
    __syncthreads();

    int cur = 0;
    for (int k0 = 0; k0 < DIM; k0 += BK) {
        if (k0 + BK < DIM) {       // prefetch next K-tile into buf^1
            #pragma unroll
            for (int i = 0; i < 4; ++i) {
                const int rb = i * 32 + wv * 8;
                gload16(&A[(size_t)(m0 + rb + lrow) * DIM + k0 + BK + lch],
                        &Ah[cur ^ 1][rb][0]);
                gload16(&B[(size_t)(n0 + rb + lrow) * DIM + k0 + BK + lch],
                        &Bh[cur ^ 1][rb][0]);
            }
        }

        #pragma unroll
        for (int ks = 0; ks < BK; ks += 32) {
            const int koff = ks + ((lane >> 4) << 3);
            const int rs = lane & 15;
            bf16x8 af[4], bf[4];
            #pragma unroll
            for (int i = 0; i < 4; ++i) {
                af[i] = *(const bf16x8*)&Ah[cur][wm + i * 16 + rs][koff];
                bf[i] = *(const bf16x8*)&Bh[cur][wn + i * 16 + rs][koff];
            }
            #pragma unroll
            for (int i = 0; i < 4; ++i)
                #pragma unroll
                for (int j = 0; j < 4; ++j)
                    acc[i][j] = __builtin_amdgcn_mfma_f32_16x16x32_bf16(
                        af[i], bf[j], acc[i][j], 0, 0, 0);
        }
        __syncthreads();   // drains vmcnt (prefetch landed, hidden) + lgkm;
        cur ^= 1;          // all waves done reading old buf
    }

    const int rsel  = lane & 15;
    const int quad  = lane >> 4;
    const int rbase = m0 + wm + (quad << 2);
    const int c0    = n0 + wn;          // 64-aligned -> one (t,h) per wave
    const int tt    = c0 / DIM;
    const int h     = (c0 % DIM) >> 6;

    if (tt == 2) {
        // key kappa (within 64-tile) = 16i + 4quad + r -> slot 16quad + 4r + i
        const int T = (m0 + wm) >> 6;
        #pragma unroll
        for (int j = 0; j < 4; ++j) {
            const int d = rsel + 16 * j;
            ushort vv[16];
            #pragma unroll
            for (int r = 0; r < 4; ++r)
                #pragma unroll
                for (int i = 0; i < 4; ++i)
                    vv[4 * r + i] = f2bf(acc[i][j][r]);
            ushort* dst = &Vp[((size_t)h * HD + d) * SEQ + T * 64 + 16 * quad];
            *(float4*)&dst[0] = *(const float4*)&vv[0];
            *(float4*)&dst[8] = *(const float4*)&vv[8];
        }
    } else {
        ushort* dstb = (tt == 0 ? Qb : Kb) + (size_t)h * SEQ * HD;
        // 0.125 * log2(e): flash computes exp(S) via v_exp_f32 (2^S').
        const float qs = (tt == 0) ? 0.18033688011112042f : 1.0f;
        #pragma unroll
        for (int i = 0; i < 4; ++i)
            #pragma unroll
            for (int r = 0; r < 4; ++r) {
                const int n = rbase + i * 16 + r;
                #pragma unroll
                for (int j = 0; j < 2; ++j) {
                    const float a = acc[i][j][r];
                    const float b = acc[i][j + 2][r];
                    const float2 cs2 = tab[n * 32 + rsel + 16 * j];
                    dstb[(size_t)n * HD + rsel + 16 * j]      = f2bf((a * cs2.x - b * cs2.y) * qs);
                    dstb[(size_t)n * HD + rsel + 16 * j + 32] = f2bf((b * cs2.x + a * cs2.y) * qs);
                }
            }
    }
}

// ---------------------------------------------------------------------------
// MFMA flash attention — T1 XCD swizzle + T3 2-phase dbuf. FROZEN from r7
// (81.9 us, MfmaUtil 26.5, FETCH 12.3 MB, WRITE 25 MB).
// ---------------------------------------------------------------------------
__global__ __launch_bounds__(256, 3)
void flash_mfma(const ushort* __restrict__ Qb, const ushort* __restrict__ Kb,
                const ushort* __restrict__ Vp,
                float* __restrict__ Opart, float* __restrict__ lpart)
{
    __shared__ ushort Ks[2][64][68];   // [buf][key][d]
    __shared__ ushort Vs[2][64][68];   // [buf][d][slot]
    __shared__ ushort Pl[4][32][68];   // per-wave P, [row][slot]

    const int t    = threadIdx.x;
    const int lane = t & 63;
    const int wv   = t >> 6;
    const int rsel = lane & 15;
    const int quad = lane >> 4;

    // T1 XCD swizzle: flat dispatch id p -> (q-tile xq, group g=(h,part))
    // such that all 32 xq of a group share p%8 (= the XCD on round-robin HW).
    const int p  = blockIdx.x + 32 * (blockIdx.y + 12 * blockIdx.z);
    const int c  = p & 7;              // xcd slot
    const int r  = p >> 3;             // 0..95 position within xcd
    const int gi = r >> 5;             // 0..2  group index within xcd
    const int xq = r & 31;             // q-tile
    const int g  = gi * 8 + c;         // 0..23 (h,part) group
    const int h    = g % 12;
    const int part = g / 12;

    const int q0   = xq * 128 + wv * 32;
    const int Tbeg = (part * (SEQ / KSPLIT)) >> 6;
    const int Tend = Tbeg + (SEQ / KSPLIT) / 64;

    const int crow = t >> 2;           // 0..63 staging row
    const int ccol = (t & 3) * 16;     // 0/16/32/48 ushorts (2x16B per thread)

    // Q A-frags (persistent)
    bf16x8 aq[2][2];
    #pragma unroll
    for (int mi = 0; mi < 2; ++mi)
        #pragma unroll
        for (int ks = 0; ks < 2; ++ks)
            aq[mi][ks] = *(const bf16x8*)&Qb[((size_t)h * SEQ + q0 + 16 * mi + rsel) * HD
                                             + ks * 32 + quad * 8];

    f32x4 accO[2][4] = {};
    float lsum[2][4] = {};

    // prologue: stage tile Tbeg into buf 0
    {
        const ushort* ksrc = &Kb[((size_t)h * SEQ + Tbeg * 64 + crow) * HD + ccol];
        const float4 k0 = *(const float4*)&ksrc[0];
        const float4 k1 = *(const float4*)&ksrc[8];
        const ushort* vsrc = &Vp[((size_t)h * HD + crow) * SEQ + Tbeg * 64 + ccol];
        const float4 v0 = *(const float4*)&vsrc[0];
        const float4 v1 = *(const float4*)&vsrc[8];
        *(float4*)&Ks[0][crow][ccol]     = k0;
        *(float4*)&Ks[0][crow][ccol + 8] = k1;
        *(float4*)&Vs[0][crow][ccol]     = v0;
        *(float4*)&Vs[0][crow][ccol + 8] = v1;
    }
    __syncthreads();

    int cur = 0;
    for (int T = Tbeg; T < Tend; ++T) {
        // issue next-tile K/V loads (clamped on last iter: re-reads own tile,
        // L2-hot, harmless). In flight across the whole compute below.
        const int Tn = (T + 1 < Tend) ? T + 1 : T;
        const ushort* ksrc = &Kb[((size_t)h * SEQ + Tn * 64 + crow) * HD + ccol];
        const float4 kn0 = *(const float4*)&ksrc[0];
        const float4 kn1 = *(const float4*)&ksrc[8];
        const ushort* vsrc = &Vp[((size_t)h * HD + crow) * SEQ + Tn * 64 + ccol];
        const float4 vn0 = *(const float4*)&vsrc[0];
        const float4 vn1 = *(const float4*)&vsrc[8];

        // K and V B-frags from LDS buf[cur] (shared across both M-halves)
        bf16x8 bk[4][2], bv[4][2];
        #pragma unroll
        for (int n = 0; n < 4; ++n)
            #pragma unroll
            for (int ks = 0; ks < 2; ++ks) {
                bk[n][ks] = *(const bf16x8*)&Ks[cur][16 * n + rsel][32 * ks + quad * 8];
                bv[n][ks] = *(const bf16x8*)&Vs[cur][16 * n + rsel][32 * ks + quad * 8];
            }

        #pragma unroll
        for (int mi = 0; mi < 2; ++mi) {
            f32x4 accS[4] = {};
            #pragma unroll
            for (int ks = 0; ks < 2; ++ks)
                #pragma unroll
                for (int n = 0; n < 4; ++n)
                    accS[n] = __builtin_amdgcn_mfma_f32_16x16x32_bf16(
                        aq[mi][ks], bk[n][ks], accS[n], 0, 0, 0);

            // P = 2^S (log2e folded into Q); packed write,
            // slot s = 4rsel + n (key = 16n + rsel)
            #pragma unroll
            for (int r = 0; r < 4; ++r) {
                const float p0 = __builtin_amdgcn_exp2f(accS[0][r]);
                const float p1 = __builtin_amdgcn_exp2f(accS[1][r]);
                const float p2 = __builtin_amdgcn_exp2f(accS[2][r]);
                const float p3 = __builtin_amdgcn_exp2f(accS[3][r]);
                ushort4 pw;
                pw.x = f2bf_tw(p0); pw.y = f2bf_tw(p1);
                pw.z = f2bf_tw(p2); pw.w = f2bf_tw(p3);
                *(ushort4*)&Pl[wv][16 * mi + 4 * quad + r][4 * rsel] = pw;
                lsum[mi][r] += (p0 + p1) + (p2 + p3);
            }
        }

        // wave-private LDS RAW: drain writes before A-frag reads (once/tile)
        asm volatile("s_waitcnt lgkmcnt(0)" ::: "memory");

        #pragma unroll
        for (int mi = 0; mi < 2; ++mi) {
            bf16x8 ap[2];
            ap[0] = *(const bf16x8*)&Pl[wv][16 * mi + rsel][quad * 8];
            ap[1] = *(const bf16x8*)&Pl[wv][16 * mi + rsel][32 + quad * 8];
            #pragma unroll
            for (int ks = 0; ks < 2; ++ks)
                #pragma unroll
                for (int j = 0; j < 4; ++j)
                    accO[mi][j] = __builtin_amdgcn_mfma_f32_16x16x32_bf16(
                        ap[ks], bv[j][ks], accO[mi][j], 0, 0, 0);
        }

        // write staged tile T+1 into buf[cur^1] (vmcnt wait lands here —
        // loads issued ~600cy ago; cur^1 dead since prior-tile barrier).
        *(float4*)&Ks[cur ^ 1][crow][ccol]     = kn0;
        *(float4*)&Ks[cur ^ 1][crow][ccol + 8] = kn1;
        *(float4*)&Vs[cur ^ 1][crow][ccol]     = vn0;
        *(float4*)&Vs[cur ^ 1][crow][ccol + 8] = vn1;
        __syncthreads();               // drains ds_writes, publishes buf[cur^1]
        cur ^= 1;
    }

    // one-time l reduction across rsel lanes
    #pragma unroll
    for (int mi = 0; mi < 2; ++mi)
        #pragma unroll
        for (int r = 0; r < 4; ++r) {
            float s = lsum[mi][r];
            s += __shfl_xor(s, 1);
            s += __shfl_xor(s, 2);
            s += __shfl_xor(s, 4);
            s += __shfl_xor(s, 8);
            lsum[mi][r] = s;
        }

    float* Ob = Opart + ((size_t)part * NHEADS + h) * SEQ * HD;
    float* lb = lpart + ((size_t)part * NHEADS + h) * SEQ;
    #pragma unroll
    for (int mi = 0; mi < 2; ++mi)
        #pragma unroll
        for (int r = 0; r < 4; ++r) {
            const int n = q0 + 16 * mi + 4 * quad + r;
            #pragma unroll
            for (int j = 0; j < 4; ++j)
                Ob[(size_t)n * HD + 16 * j + rsel] = accO[mi][j][r];
            if (rsel == 0) lb[n] = lsum[mi][r];
        }
}

// ---------------------------------------------------------------------------
// Split-K merge: AO[n][h*64+d] = (sum_p Opart) / (sum_p l), bf16.
// ---------------------------------------------------------------------------
__global__ __launch_bounds__(256)
void merge_k(const float* __restrict__ Opart, const float* __restrict__ lpart,
             ushort* __restrict__ AO)
{
    const int idx = blockIdx.x * 256 + threadIdx.x;
    const int dg = idx & 15;
    const int n  = (idx >> 4) & (SEQ - 1);
    const int h  = idx >> 16;

    float4 o = make_float4(0.f, 0.f, 0.f, 0.f);
    float l = 0.f;
    #pragma unroll
    for (int p = 0; p < KSPLIT; ++p) {
        const float4 v = *(const float4*)&Opart[(((size_t)p * NHEADS + h) * SEQ + n) * HD + dg * 4];
        o.x += v.x; o.y += v.y; o.z += v.z; o.w += v.w;
        l += lpart[((size_t)p * NHEADS + h) * SEQ + n];
    }
    const float inv = 1.f / l;
    ushort4 w;
    w.x = f2bf(o.x * inv); w.y = f2bf(o.y * inv);
    w.z = f2bf(o.z * inv); w.w = f2bf(o.w * inv);
    *(ushort4*)&AO[(size_t)n * DIM + h * HD + dg * 4] = w;
}

// ---------------------------------------------------------------------------
// Proj GEMM: out = attnout(bf16) @ proj_wb(bf16)^T + proj_b(f32), f32 out.
// T3 1-barrier double-buffered K-loop (same as gemm_qkv).
// ---------------------------------------------------------------------------
__global__ __launch_bounds__(256)
void gemm_proj(const ushort* __restrict__ A, const ushort* __restrict__ B,
               const float* __restrict__ bias, float* __restrict__ out)
{
    constexpr int BM = 128, BN = 128, BK = 64;
    __shared__ __attribute__((aligned(16))) ushort As[2][BM][BK];
    __shared__ __attribute__((aligned(16))) ushort Bs[2][BN][BK];

    const int t    = threadIdx.x;
    const int lane = t & 63;
    const int wv   = t >> 6;
    const int wm   = (wv >> 1) * 64;
    const int wn   = (wv & 1) * 64;
    const int m0   = blockIdx.y * BM;
    const int n0   = blockIdx.x * BN;

    f32x4 acc[4][4] = {};

    const int lrow = lane >> 3;
    const int lch  = (lane & 7) * 8;

    #pragma unroll
    for (int i = 0; i < 4; ++i) {
        const int rb = i * 32 + wv * 8;
        gload16(&A[(size_t)(m0 + rb + lrow) * DIM + lch], &As[0][rb][0]);
        gload16(&B[(size_t)(n0 + rb + lrow) * DIM + lch], &Bs[0][rb][0]);
    }
    __syncthreads();

    int cur = 0;
    for (int k0 = 0; k0 < DIM; k0 += BK) {
        if (k0 + BK < DIM) {
            #pragma unroll
            for (int i = 0; i < 4; ++i) {
                const int rb = i * 32 + wv * 8;
                gload16(&A[(size_t)(m0 + rb + lrow) * DIM + k0 + BK + lch],
                        &As[cur ^ 1][rb][0]);
                gload16(&B[(size_t)(n0 + rb + lrow) * DIM + k0 + BK + lch],
                        &Bs[cur ^ 1][rb][0]);
            }
        }

        #pragma unroll
        for (int ks = 0; ks < BK; ks += 32) {
            const int koff = ks + ((lane >> 4) << 3);
            const int rs = lane & 15;
            bf16x8 af[4], bf[4];
            #pragma unroll
            for (int i = 0; i < 4; ++i) {
                af[i] = *(const bf16x8*)&As[cur][wm + i * 16 + rs][koff];
                bf[i] = *(const bf16x8*)&Bs[cur][wn + i * 16 + rs][koff];
            }
            #pragma unroll
            for (int i = 0; i < 4; ++i)
                #pragma unroll
                for (int j = 0; j < 4; ++j)
                    acc[i][j] = __builtin_amdgcn_mfma_f32_16x16x32_bf16(
                        af[i], bf[j], acc[i][j], 0, 0, 0);
        }
        __syncthreads();
        cur ^= 1;
    }

    const int rbase = m0 + wm + ((lane >> 4) << 2);
    const int cbase = n0 + wn + (lane & 15);

    #pragma unroll
    for (int j = 0; j < 4; ++j) {
        const int col = cbase + j * 16;
        const float bv = bias[col];
        #pragma unroll
        for (int i = 0; i < 4; ++i) {
            const int row0 = rbase + i * 16;
            #pragma unroll
            for (int r = 0; r < 4; ++r)
                out[(size_t)(row0 + r) * DIM + col] = acc[i][j][r] + bv;
        }
    }
}

// ---------------------------------------------------------------------------
extern "C" void kernel_launch(void* const* d_in, const int* in_sizes, int n_in,
                              void* d_out, int out_size, void* d_ws, size_t ws_size,
                              hipStream_t stream)
{
    const float* x      = (const float*)d_in[0];
    const float* qkv_w  = (const float*)d_in[1];
    const float* proj_w = (const float*)d_in[2];
    const float* proj_b = (const float*)d_in[3];

    const size_t headsz = (size_t)NHEADS * SEQ * HD;       // 3,145,728
    char* p = (char*)d_ws;
    ushort* Qb    = (ushort*)p;                 p += headsz * 2;
    ushort* Kb    = (ushort*)p;                 p += headsz * 2;
    ushort* Vp    = (ushort*)p;                 p += headsz * 2;
    ushort* AO    = (ushort*)p;                 p += (size_t)SEQ * DIM * 2;
    float*  Opart = (float*)p;                  p += (size_t)KSPLIT * headsz * 4;
    float*  lpart = (float*)p;                  p += (size_t)KSPLIT * NHEADS * SEQ * 4;
    float2* tab   = (float2*)p;                 p += (size_t)SEQ * 32 * sizeof(float2);
    ushort* xb    = (ushort*)p;                 p += (size_t)SEQ * DIM * 2;
    ushort* qwb   = (ushort*)p;                 p += (size_t)3 * DIM * DIM * 2;
    ushort* pwb   = (ushort*)p;
    float*  out   = (float*)d_out;

    prep<<<5888, 256, 0, stream>>>(x, qkv_w, proj_w, xb, qwb, pwb, tab);

    gemm_qkv<<<dim3(3 * DIM / 128, SEQ / 128), 256, 0, stream>>>(
        xb, qwb, tab, Qb, Kb, Vp);

    flash_mfma<<<dim3(SEQ / 128, NHEADS, KSPLIT), 256, 0, stream>>>(
        Qb, Kb, Vp, Opart, lpart);

    merge_k<<<(NHEADS * SEQ * 16) / 256, 256, 0, stream>>>(Opart, lpart, AO);

    gemm_proj<<<dim3(DIM / 128, SEQ / 128), 256, 0, stream>>>(
        AO, pwb, proj_b, out);
}